// Round 19
// baseline (236.617 us; speedup 1.0000x reference)
//
#include <hip/hip_runtime.h>
#include <hip/hip_bf16.h>
#include <stdint.h>

#define B_  4
#define S_  2048
#define H_  1024
#define NH_ 16
#define DK_ 64
#define M_  (B_*S_)   // 8192

typedef unsigned short u16;
typedef __attribute__((ext_vector_type(8))) short bfrag;     // 8 x bf16 (4 VGPRs)
typedef __attribute__((ext_vector_type(4))) float facc;      // 4 x f32
typedef __attribute__((ext_vector_type(16))) float f32x16;   // 32x32 accumulator
typedef __attribute__((ext_vector_type(4))) unsigned int u32x4;
typedef __attribute__((ext_vector_type(2))) unsigned int u32x2;

__device__ __forceinline__ u16 f2bf(float f) {
  uint32_t u = __float_as_uint(f);
  return (u16)((u + 0x7fffu + ((u >> 16) & 1u)) >> 16);    // RNE
}

__device__ __forceinline__ uint32_t cvtpk_bf16(float a, float b) {
  uint32_t r;
  asm("v_cvt_pk_bf16_f32 %0, %1, %2" : "=v"(r) : "v"(a), "v"(b));
  return r;
}

// ---------------- prep: weight cvt (4) + mask pack ----------------
// Activations are NO LONGER pre-converted: qkv_gemm reads f32 directly
// (removes 144 MB of HBM round-trip; prep was at the HBM roofline).
// blocks [0,1024): weights; [1024,17408): mask pack (gather, linear writes).
__global__ __launch_bounds__(256) void prep_kernel(
    const float* __restrict__ Wq, const float* __restrict__ Wk,
    const float* __restrict__ Wv, const float* __restrict__ Wo,
    const int* __restrict__ mask,
    u16* __restrict__ wqo, u16* __restrict__ wko, u16* __restrict__ wvo, u16* __restrict__ woo,
    uint32_t* __restrict__ mbytes, float qscale) {
  const int bid = blockIdx.x;
  const int tid = threadIdx.x;
  if (bid < 1024) {
    int seg = bid >> 8, sb = bid & 255;
    const float* in = seg == 0 ? Wq : seg == 1 ? Wk : seg == 2 ? Wv : Wo;
    u16* out = seg == 0 ? wqo : seg == 1 ? wko : seg == 2 ? wvo : woo;
    float sc = (seg == 0) ? qscale : 1.0f;
    const int n4 = H_ * H_ / 4;
    for (int i = sb*256 + tid; i < n4; i += 256*256) {
      float4 v = reinterpret_cast<const float4*>(in)[i];
      ushort4 o;
      o.x = f2bf(v.x * sc); o.y = f2bf(v.y * sc);
      o.z = f2bf(v.z * sc); o.w = f2bf(v.w * sc);
      reinterpret_cast<ushort4*>(out)[i] = o;
    }
  } else {
    // mask pack, gather: out dword index od is LINEAR (coalesced stores).
    // Layout [qblk][c][wave][hl][l31][j].
    int od = (bid - 1024)*256 + tid;                   // 0 .. B*S*512-1
    int j = od & 7, l31q = (od >> 3) & 31, hl = (od >> 8) & 1;
    int wv_ = (od >> 9) & 3, c = (od >> 11) & 31, qblk = od >> 16;
    int bq = qblk*128 + wv_*32 + l31q;
    int4 v = *reinterpret_cast<const int4*>(mask + (size_t)bq*2048 + c*64 + 4*hl + 8*(j & 3) + 32*(j >> 2));
    uint32_t w = (v.x != 0 ? 1u : 0u) | (v.y != 0 ? 0x100u : 0u) |
                 (v.z != 0 ? 0x10000u : 0u) | (v.w != 0 ? 0x1000000u : 0u);
    mbytes[od] = w;
  }
}

#define GLD16(gsrc, ldst) \
  __builtin_amdgcn_global_load_lds((const __attribute__((address_space(1))) void*)(gsrc), \
                                   (__attribute__((address_space(3))) void*)(ldst), 16, 0, 0)

// bf16-A GEMM K-loop (BK=64, XOR-swizzled LDS) — used by gemm_out.
#define GEMM_KLOOP(A_, B_, As_, Bs_) \
  for (int k0 = 0; k0 < K; k0 += 64) { \
    const u16* Ab = (A_) + (size_t)m0 * K + k0; \
    const u16* Bb = (B_) + (size_t)n0 * K + k0; \
    _Pragma("unroll") \
    for (int i = 0; i < 4; i++) { \
      int idx = i*256 + tid; \
      int row = idx >> 3, q = idx & 7; \
      int qs = q ^ (row & 7); \
      char* la = (char*)(As_) + i*4096 + wave*1024; \
      char* lb = (char*)(Bs_) + i*4096 + wave*1024; \
      GLD16(Ab + (size_t)row*K + qs*8, la); \
      GLD16(Bb + (size_t)row*K + qs*8, lb); \
    } \
    __syncthreads(); \
    const int sa = (lo & 7) << 4; \
    _Pragma("unroll") \
    for (int kk = 0; kk < 2; kk++) { \
      bfrag af[4], bfv[4]; \
      _Pragma("unroll") \
      for (int t = 0; t < 4; t++) { \
        af[t]  = *reinterpret_cast<const bfrag*>((char*)(As_) + (wr*64 + t*16 + lo)*128 + ((kk*64 + hi*16) ^ sa)); \
        bfv[t] = *reinterpret_cast<const bfrag*>((char*)(Bs_) + (wc*64 + t*16 + lo)*128 + ((kk*64 + hi*16) ^ sa)); \
      } \
      _Pragma("unroll") \
      for (int mt = 0; mt < 4; mt++) \
        _Pragma("unroll") \
        for (int nt = 0; nt < 4; nt++) \
          acc[mt][nt] = __builtin_amdgcn_mfma_f32_16x16x32_bf16(af[mt], bfv[nt], acc[mt][nt], 0, 0, 0); \
    } \
    __syncthreads(); \
  }

// ---------------- Fused QKV projection GEMM, f32 A direct ----------------
// A staged as f32 (32 KB, swizzled slots: slot q holds col-chunk q^(row&7));
// fragments converted to bf16 at read time via v_cvt_pk_bf16_f32.
__global__ __launch_bounds__(256) void qkv_gemm(const float* __restrict__ qa, const float* __restrict__ ka,
                                                const float* __restrict__ va,
                                                const u16* __restrict__ Wqb, const u16* __restrict__ Wkb,
                                                const u16* __restrict__ Wvb,
                                                const float* __restrict__ bqp, const float* __restrict__ bkp,
                                                const float* __restrict__ bvp, float qbscale,
                                                u16* __restrict__ qh, u16* __restrict__ kh,
                                                u16* __restrict__ vt) {
  constexpr int K = H_;
  __shared__ __align__(16) float Asf[128*64];          // 32 KB f32 A tile
  __shared__ __align__(16) u16  Bs[128*64];            // 16 KB bf16 B tile
  const int tid = threadIdx.x;
  const int lane = tid & 63, wave = tid >> 6;
  const int lo = lane & 15, hi = lane >> 4;
  const int wr = wave >> 1, wc = wave & 1;
  const int wsel = blockIdx.y >> 3;
  const int m0 = blockIdx.x * 128, n0 = (blockIdx.y & 7) * 128;
  const float* A = wsel == 0 ? qa : wsel == 1 ? ka : va;
  const u16* Bm = wsel == 0 ? Wqb : wsel == 1 ? Wkb : Wvb;
  const float* bias = wsel == 0 ? bqp : wsel == 1 ? bkp : bvp;
  const float bscale = wsel == 0 ? qbscale : 1.0f;
  facc acc[4][4] = {};

  for (int k0 = 0; k0 < K; k0 += 64) {
    const float* Ab = A + (size_t)m0 * K + k0;
    const u16* Bb = Bm + (size_t)n0 * K + k0;
    #pragma unroll
    for (int i = 0; i < 8; i++) {           // A: 128 rows x 64 f32, 16 slots/row
      int idx = i*256 + tid;
      int row = idx >> 4, q = idx & 15;
      int qs = q ^ (row & 7);
      char* la = (char*)Asf + i*4096 + wave*1024;
      GLD16((const char*)(Ab + (size_t)row*K) + qs*16, la);
    }
    #pragma unroll
    for (int i = 0; i < 4; i++) {           // B: bf16, 8 slots/row
      int idx = i*256 + tid;
      int row = idx >> 3, q = idx & 7;
      int qs = q ^ (row & 7);
      char* lb = (char*)Bs + i*4096 + wave*1024;
      GLD16(Bb + (size_t)row*K + qs*8, lb);
    }
    __syncthreads();
    const int sa = (lo & 7) << 4;
    const int s8 = lo & 7;
    #pragma unroll
    for (int kk = 0; kk < 2; kk++) {
      bfrag af[4], bfv[4];
      #pragma unroll
      for (int t = 0; t < 4; t++) {
        int ra = wr*64 + t*16 + lo;         // ra & 7 == lo & 7
        const char* rowp = (const char*)Asf + ra*256;
        float4 x = *reinterpret_cast<const float4*>(rowp + (((kk*8 + hi*2 + 0) ^ s8) * 16));
        float4 y = *reinterpret_cast<const float4*>(rowp + (((kk*8 + hi*2 + 1) ^ s8) * 16));
        u32x4 pk;
        pk[0] = cvtpk_bf16(x.x, x.y); pk[1] = cvtpk_bf16(x.z, x.w);
        pk[2] = cvtpk_bf16(y.x, y.y); pk[3] = cvtpk_bf16(y.z, y.w);
        af[t] = __builtin_bit_cast(bfrag, pk);
        bfv[t] = *reinterpret_cast<const bfrag*>((char*)Bs + (wc*64 + t*16 + lo)*128 + ((kk*64 + hi*16) ^ sa));
      }
      #pragma unroll
      for (int mt = 0; mt < 4; mt++)
        #pragma unroll
        for (int nt = 0; nt < 4; nt++)
          acc[mt][nt] = __builtin_amdgcn_mfma_f32_16x16x32_bf16(af[mt], bfv[nt], acc[mt][nt], 0, 0, 0);
    }
    __syncthreads();
  }

  if (wsel < 2) {
    u16* o = wsel == 0 ? qh : kh;
    #pragma unroll
    for (int nt = 0; nt < 4; nt++) {
      int n = n0 + wc*64 + nt*16 + lo;
      float bv = bias[n] * bscale;
      int hh = n >> 6, d = n & 63;
      #pragma unroll
      for (int mt = 0; mt < 4; mt++) {
        #pragma unroll
        for (int r = 0; r < 4; r++) {
          int m = m0 + wr*64 + mt*16 + hi*4 + r;
          int bb = m >> 11, s = m & (S_ - 1);
          o[(((size_t)bb*NH_ + hh)*S_ + s)*DK_ + d] = f2bf(acc[mt][nt][r] + bv);
        }
      }
    }
  } else {
    // V: tile -> LDS [64 d][128 s] (XOR-swizzled) -> coalesced d-major global writes.
    u16* scr = (u16*)Asf;                   // 16 KB needed of the 32 KB A buffer
    const int bb2 = m0 >> 11, s0r = m0 & (S_ - 1);
    #pragma unroll
    for (int p = 0; p < 2; p++) {           // head within n-range = wc
      __syncthreads();
      if (wc == p) {
        #pragma unroll
        for (int nt = 0; nt < 4; nt++) {
          int d = nt*16 + lo;
          float bv = bias[n0 + p*64 + d];
          #pragma unroll
          for (int mt = 0; mt < 4; mt++) {
            #pragma unroll
            for (int r = 0; r < 4; r++) {
              int s = wr*64 + mt*16 + hi*4 + r;
              *(u16*)((char*)scr + d*256 + ((s*2) ^ ((d & 7) << 4))) = f2bf(acc[mt][nt][r] + bv);
            }
          }
        }
      }
      __syncthreads();
      int hh = (n0 >> 6) + p;
      u16* vbase = vt + ((size_t)bb2*NH_ + hh) * DK_ * S_ + s0r;
      #pragma unroll
      for (int i = 0; i < 4; i++) {
        int idx = i*256 + tid;
        int d = idx >> 4, sc = idx & 15;
        bfrag v = *reinterpret_cast<const bfrag*>((char*)scr + d*256 + ((sc*16) ^ ((d & 7) << 4)));
        *reinterpret_cast<bfrag*>(vbase + (size_t)d*S_ + sc*8) = v;
      }
    }
  }
}

// ---------------- Output projection GEMM: out = xb @ Wo^T + bo (f32) ----------------
__global__ __launch_bounds__(256) void gemm_out(const u16* __restrict__ A, const u16* __restrict__ Bm,
                                                const float* __restrict__ bias, float* __restrict__ o) {
  constexpr int K = H_, N = H_;
  __shared__ __align__(16) u16 As[128*64];
  __shared__ __align__(16) u16 Bs[128*64];
  const int tid = threadIdx.x;
  const int lane = tid & 63, wave = tid >> 6;
  const int lo = lane & 15, hi = lane >> 4;
  const int wr = wave >> 1, wc = wave & 1;
  const int m0 = blockIdx.x * 128, n0 = blockIdx.y * 128;
  facc acc[4][4] = {};

  GEMM_KLOOP(A, Bm, As, Bs)

  #pragma unroll
  for (int nt = 0; nt < 4; nt++) {
    int n = n0 + wc*64 + nt*16 + lo;
    float bv = bias[n];
    #pragma unroll
    for (int mt = 0; mt < 4; mt++) {
      #pragma unroll
      for (int r = 0; r < 4; r++) {
        int m = m0 + wr*64 + mt*16 + hi*4 + r;
        o[(size_t)m*N + n] = acc[mt][nt][r] + bv;
      }
    }
  }
}

// ---------------- Flash attention v7c: fixed-M softmax, coalesced mask reads ----------------
__global__ __launch_bounds__(256, 4) void attn_kernel(const u16* __restrict__ Qh, const u16* __restrict__ Kh,
                                                      const u16* __restrict__ Vt, const uint32_t* __restrict__ mbytes,
                                                      u16* __restrict__ xout) {
  __shared__ __align__(16) u16 Ks[2][64*64];   // 8 KiB each, XOR-swizzled rows of 128 B
  __shared__ __align__(16) u16 Vs[2][64*64];
  const int tid = threadIdx.x;
  const int lane = tid & 63, wave = tid >> 6;
  const int l31 = lane & 31, hl = lane >> 5;
  const int gid = blockIdx.x;                  // XCD-bijective swizzle: 8 bh per XCD, qt inner
  const int bh = (gid & 7) * 8 + (gid >> 7);
  const int qt = (gid >> 3) & 15;
  const int b = bh >> 4, hd = bh & 15;
  const int q0 = qt * 128;
  const size_t bhS = (size_t)bh * S_;
  const int swz = (lane & 7) << 4;

  bfrag qf[4];
  {
    const u16* qrow = Qh + (bhS + q0 + wave*32 + l31) * DK_;
    #pragma unroll
    for (int t = 0; t < 4; t++) qf[t] = *reinterpret_cast<const bfrag*>(qrow + t*16 + hl*8);
  }
  // coalesced mask base: [qblk][c][wave][hl][l31][32B]; wave's chunk-read = contiguous 2 KB
  const int qblk = b*16 + qt;
  const char* mrowb = (const char*)mbytes + (size_t)qblk*262144 + wave*2048 + hl*1024 + l31*32;

  const int srow = wave*8 + (lane >> 3);
  const int scol = ((lane & 7) ^ (lane >> 3)) * 16;
  const char* ksrc = (const char*)(Kh + bhS * DK_) + (size_t)srow * 128 + scol;
  const char* vsrc = (const char*)(Vt + (size_t)bh * DK_ * S_) + (size_t)srow * (S_*2) + scol;

#define STAGE(buf, c) { \
    char* kl = (char*)Ks[buf] + wave*1024; \
    char* vl = (char*)Vs[buf] + wave*1024; \
    GLD16(ksrc + (size_t)(c)*8192,          kl); \
    GLD16(ksrc + (size_t)(c)*8192 + 4096,   kl + 4096); \
    GLD16(vsrc + (size_t)(c)*128,           vl); \
    GLD16(vsrc + (size_t)(c)*128 + 131072,  vl + 4096); \
  }

  float l_run = 0.f;                           // per-half-lane partial denominator
  f32x16 accO[2];
  #pragma unroll
  for (int e = 0; e < 16; e++) { accO[0][e] = 0.f; accO[1][e] = 0.f; }

  STAGE(0, 0);
  u32x4 mA_cur = *reinterpret_cast<const u32x4*>(mrowb);
  u32x4 mB_cur = *reinterpret_cast<const u32x4*>(mrowb + 16);
  __syncthreads();

  for (int c = 0; c < 32; c++) {
    const int cur = c & 1;
    if (c + 1 < 32) STAGE(cur ^ 1, c + 1);

    u32x4 mA = mA_cur, mB = mB_cur;
    if (c + 1 < 32) {
      const char* mn = mrowb + (size_t)(c + 1)*8192;
      mA_cur = *reinterpret_cast<const u32x4*>(mn);
      mB_cur = *reinterpret_cast<const u32x4*>(mn + 16);
    }

    // ---- C-init = -M - 1e36*maskbyte ----
    f32x16 s0, s1;
    #pragma unroll
    for (int r = 0; r < 16; r++) {
      float f0 = (float)((mA[r >> 2] >> ((r & 3) * 8)) & 0xffu);
      float f1 = (float)((mB[r >> 2] >> ((r & 3) * 8)) & 0xffu);
      s0[r] = __builtin_fmaf(f0, -1e36f, -8.0f);
      s1[r] = __builtin_fmaf(f1, -1e36f, -8.0f);
    }

    // ---- QK^T swapped ----
    const char* KsB = (const char*)Ks[cur];
    __builtin_amdgcn_s_setprio(1);
    #pragma unroll
    for (int t = 0; t < 4; t++) {
      bfrag k0 = *reinterpret_cast<const bfrag*>(KsB + l31*128        + ((t*32 + hl*16) ^ swz));
      bfrag k1 = *reinterpret_cast<const bfrag*>(KsB + (32 + l31)*128 + ((t*32 + hl*16) ^ swz));
      s0 = __builtin_amdgcn_mfma_f32_32x32x16_bf16(k0, qf[t], s0, 0, 0, 0);
      s1 = __builtin_amdgcn_mfma_f32_32x32x16_bf16(k1, qf[t], s1, 0, 0, 0);
    }
    __builtin_amdgcn_s_setprio(0);

    // ---- p = 2^s directly ----
    #pragma unroll
    for (int r = 0; r < 16; r++) {
      s0[r] = __builtin_amdgcn_exp2f(s0[r]);
      s1[r] = __builtin_amdgcn_exp2f(s1[r]);
    }
    float a8[8];
    #pragma unroll
    for (int r = 0; r < 8; r++) a8[r] = (s0[r] + s0[r+8]) + (s1[r] + s1[r+8]);
    l_run += ((a8[0] + a8[1]) + (a8[2] + a8[3])) + ((a8[4] + a8[5]) + (a8[6] + a8[7]));

    // ---- P -> PV A-frags in-register ----
    u32x4 pa[4];
    #pragma unroll
    for (int kt = 0; kt < 2; kt++) {
      uint32_t W[8];
      #pragma unroll
      for (int j = 0; j < 8; j++)
        W[j] = kt == 0 ? cvtpk_bf16(s0[2*j], s0[2*j+1]) : cvtpk_bf16(s1[2*j], s1[2*j+1]);
      u32x2 r02 = __builtin_amdgcn_permlane32_swap(W[0], W[2], false, false);
      u32x2 r13 = __builtin_amdgcn_permlane32_swap(W[1], W[3], false, false);
      u32x2 r46 = __builtin_amdgcn_permlane32_swap(W[4], W[6], false, false);
      u32x2 r57 = __builtin_amdgcn_permlane32_swap(W[5], W[7], false, false);
      pa[kt*2    ][0] = r02[0]; pa[kt*2    ][1] = r13[0]; pa[kt*2    ][2] = r02[1]; pa[kt*2    ][3] = r13[1];
      pa[kt*2 + 1][0] = r46[0]; pa[kt*2 + 1][1] = r57[0]; pa[kt*2 + 1][2] = r46[1]; pa[kt*2 + 1][3] = r57[1];
    }

    // ---- PV ----
    const char* VsB = (const char*)Vs[cur];
    __builtin_amdgcn_s_setprio(1);
    #pragma unroll
    for (int ks = 0; ks < 4; ks++) {
      bfrag pb = __builtin_bit_cast(bfrag, pa[ks]);
      bfrag v0 = *reinterpret_cast<const bfrag*>(VsB + l31*128        + ((ks*32 + hl*16) ^ swz));
      bfrag v1 = *reinterpret_cast<const bfrag*>(VsB + (32 + l31)*128 + ((ks*32 + hl*16) ^ swz));
      accO[0] = __builtin_amdgcn_mfma_f32_32x32x16_bf16(v0, pb, accO[0], 0, 0, 0);
      accO[1] = __builtin_amdgcn_mfma_f32_32x32x16_bf16(v1, pb, accO[1], 0, 0, 0);
    }
    __builtin_amdgcn_s_setprio(0);
    __syncthreads();
  }
#undef STAGE

  // ---- finalize ----
  float l_tot = l_run + __shfl_xor(l_run, 32);
  float linv = (l_tot > 0.f) ? (1.f / l_tot) : 0.f;
  u16* Xs = (u16*)Ks;
  {
    char* xb = (char*)Xs + (wave*32 + l31) * 128;
    #pragma unroll
    for (int dt = 0; dt < 2; dt++)
      #pragma unroll
      for (int j = 0; j < 8; j++) {
        uint32_t w = cvtpk_bf16(accO[dt][2*j] * linv, accO[dt][2*j+1] * linv);
        int d = dt*32 + ((2*j) & 3) + 8*((2*j) >> 2) + 4*hl;
        *reinterpret_cast<uint32_t*>(xb + ((d*2) ^ swz)) = w;
      }
  }
  __syncthreads();
  {
    int row = tid >> 1, d0 = (tid & 1) * 32;
    int rsw = (row & 7) << 4;
    u16* orow = xout + ((size_t)b * S_ + q0 + row) * H_ + hd * DK_ + d0;
    #pragma unroll
    for (int i = 0; i < 4; i++) {
      bfrag v = *reinterpret_cast<const bfrag*>((char*)Xs + row*128 + ((d0*2 + i*16) ^ rsw));
      *reinterpret_cast<bfrag*>((char*)orow + i*16) = v;
    }
  }
}

// ---------------- launch ----------------
extern "C" void kernel_launch(void* const* d_in, const int* in_sizes, int n_in,
                              void* d_out, int out_size, void* d_ws, size_t ws_size,
                              hipStream_t stream) {
  const float* query = (const float*)d_in[0];
  const float* key_  = (const float*)d_in[1];
  const float* value = (const float*)d_in[2];
  const int*   mask  = (const int*)d_in[3];
  const float* Wq = (const float*)d_in[4];
  const float* bq = (const float*)d_in[5];
  const float* Wk = (const float*)d_in[6];
  const float* bk = (const float*)d_in[7];
  const float* Wv = (const float*)d_in[8];
  const float* bv = (const float*)d_in[9];
  const float* Wo = (const float*)d_in[10];
  const float* bo = (const float*)d_in[11];
  float* out = (float*)d_out;

  char* ws = (char*)d_ws;
  const size_t MB = 1024 * 1024;
  u16* wq_b  = (u16*)(ws + 48*MB);    // 2 MiB each
  u16* wk_b  = (u16*)(ws + 50*MB);
  u16* wv_b  = (u16*)(ws + 52*MB);
  u16* wo_b  = (u16*)(ws + 54*MB);
  u16* qh    = (u16*)(ws + 56*MB);
  u16* kh    = (u16*)(ws + 72*MB);
  u16* vt    = (u16*)(ws + 104*MB);
  u16* xb    = (u16*)(ws + 120*MB);
  uint32_t* mbytes = (uint32_t*)(ws + 136*MB);   // 16.8 MiB mask bytes (coalesced layout)

  const float QSCALE = 0.125f * 1.44269504088896f;   // 1/sqrt(DK) * log2(e), folded into Wq/bq

  prep_kernel<<<17408, 256, 0, stream>>>(Wq, Wk, Wv, Wo, mask,
                                         wq_b, wk_b, wv_b, wo_b, mbytes, QSCALE);

  qkv_gemm<<<dim3(M_/128, 24), 256, 0, stream>>>(query, key_, value, wq_b, wk_b, wv_b,
                                                 bq, bk, bv, QSCALE, qh, kh, vt);
  attn_kernel<<<1024, 256, 0, stream>>>(qh, kh, vt, mbytes, xb);
  gemm_out<<<dim3(M_/128, H_/128), 256, 0, stream>>>(xb, wo_b, bo, out);
}

// Round 20
// 229.114 us; speedup vs baseline: 1.0327x; 1.0327x over previous
//
#include <hip/hip_runtime.h>
#include <hip/hip_bf16.h>
#include <stdint.h>

#define B_  4
#define S_  2048
#define H_  1024
#define NH_ 16
#define DK_ 64
#define M_  (B_*S_)   // 8192

typedef unsigned short u16;
typedef __attribute__((ext_vector_type(8))) short bfrag;     // 8 x bf16 (4 VGPRs)
typedef __attribute__((ext_vector_type(4))) float facc;      // 4 x f32
typedef __attribute__((ext_vector_type(16))) float f32x16;   // 32x32 accumulator
typedef __attribute__((ext_vector_type(4))) unsigned int u32x4;
typedef __attribute__((ext_vector_type(2))) unsigned int u32x2;

__device__ __forceinline__ u16 f2bf(float f) {
  uint32_t u = __float_as_uint(f);
  return (u16)((u + 0x7fffu + ((u >> 16) & 1u)) >> 16);    // RNE
}

__device__ __forceinline__ uint32_t cvtpk_bf16(float a, float b) {
  uint32_t r;
  asm("v_cvt_pk_bf16_f32 %0, %1, %2" : "=v"(r) : "v"(a), "v"(b));
  return r;
}

// ---------------- Fused prep: activation cvt (3) + weight cvt (4) + mask pack ----------------
// blocks [0,3072): activations; [3072,4096): weights; [4096,20480): mask pack (gather,
// linear coalesced writes).
__global__ __launch_bounds__(256) void prep_kernel(
    const float* __restrict__ qa, const float* __restrict__ ka, const float* __restrict__ va,
    const float* __restrict__ Wq, const float* __restrict__ Wk,
    const float* __restrict__ Wv, const float* __restrict__ Wo,
    const int* __restrict__ mask,
    u16* __restrict__ qo, u16* __restrict__ ko, u16* __restrict__ vo,
    u16* __restrict__ wqo, u16* __restrict__ wko, u16* __restrict__ wvo, u16* __restrict__ woo,
    uint32_t* __restrict__ mbytes, float qscale) {
  const int bid = blockIdx.x;
  const int tid = threadIdx.x;
  if (bid < 3072) {
    int seg = bid >> 10, sb = bid & 1023;
    const float* in = seg == 0 ? qa : seg == 1 ? ka : va;
    u16* out = seg == 0 ? qo : seg == 1 ? ko : vo;
    const int n4 = M_ * H_ / 4;
    for (int i = sb*256 + tid; i < n4; i += 1024*256) {
      float4 v = reinterpret_cast<const float4*>(in)[i];
      ushort4 o;
      o.x = f2bf(v.x); o.y = f2bf(v.y); o.z = f2bf(v.z); o.w = f2bf(v.w);
      reinterpret_cast<ushort4*>(out)[i] = o;
    }
  } else if (bid < 4096) {
    int seg = (bid - 3072) >> 8, sb = (bid - 3072) & 255;
    const float* in = seg == 0 ? Wq : seg == 1 ? Wk : seg == 2 ? Wv : Wo;
    u16* out = seg == 0 ? wqo : seg == 1 ? wko : seg == 2 ? wvo : woo;
    float sc = (seg == 0) ? qscale : 1.0f;
    const int n4 = H_ * H_ / 4;
    for (int i = sb*256 + tid; i < n4; i += 256*256) {
      float4 v = reinterpret_cast<const float4*>(in)[i];
      ushort4 o;
      o.x = f2bf(v.x * sc); o.y = f2bf(v.y * sc);
      o.z = f2bf(v.z * sc); o.w = f2bf(v.w * sc);
      reinterpret_cast<ushort4*>(out)[i] = o;
    }
  } else {
    // mask pack, gather: out dword index od is LINEAR (coalesced stores).
    // Layout [qblk][c][wave][hl][l31][j].
    int od = (bid - 4096)*256 + tid;                   // 0 .. B*S*512-1
    int j = od & 7, l31q = (od >> 3) & 31, hl = (od >> 8) & 1;
    int wv_ = (od >> 9) & 3, c = (od >> 11) & 31, qblk = od >> 16;
    int bq = qblk*128 + wv_*32 + l31q;
    int4 v = *reinterpret_cast<const int4*>(mask + (size_t)bq*2048 + c*64 + 4*hl + 8*(j & 3) + 32*(j >> 2));
    uint32_t w = (v.x != 0 ? 1u : 0u) | (v.y != 0 ? 0x100u : 0u) |
                 (v.z != 0 ? 0x10000u : 0u) | (v.w != 0 ? 0x1000000u : 0u);
    mbytes[od] = w;
  }
}

#define GLD16(gsrc, ldst) \
  __builtin_amdgcn_global_load_lds((const __attribute__((address_space(1))) void*)(gsrc), \
                                   (__attribute__((address_space(3))) void*)(ldst), 16, 0, 0)

// GEMM K-loop core, BK=64, XOR-swizzled LDS (pre-swizzled gload_lds source).
#define GEMM_KLOOP(A_, B_, As_, Bs_) \
  for (int k0 = 0; k0 < K; k0 += 64) { \
    const u16* Ab = (A_) + (size_t)m0 * K + k0; \
    const u16* Bb = (B_) + (size_t)n0 * K + k0; \
    _Pragma("unroll") \
    for (int i = 0; i < 4; i++) { \
      int idx = i*256 + tid; \
      int row = idx >> 3, q = idx & 7; \
      int qs = q ^ (row & 7); \
      char* la = (char*)(As_) + i*4096 + wave*1024; \
      char* lb = (char*)(Bs_) + i*4096 + wave*1024; \
      GLD16(Ab + (size_t)row*K + qs*8, la); \
      GLD16(Bb + (size_t)row*K + qs*8, lb); \
    } \
    __syncthreads(); \
    const int sa = (lo & 7) << 4; \
    _Pragma("unroll") \
    for (int kk = 0; kk < 2; kk++) { \
      bfrag af[4], bfv[4]; \
      _Pragma("unroll") \
      for (int t = 0; t < 4; t++) { \
        af[t]  = *reinterpret_cast<const bfrag*>((char*)(As_) + (wr*64 + t*16 + lo)*128 + ((kk*64 + hi*16) ^ sa)); \
        bfv[t] = *reinterpret_cast<const bfrag*>((char*)(Bs_) + (wc*64 + t*16 + lo)*128 + ((kk*64 + hi*16) ^ sa)); \
      } \
      _Pragma("unroll") \
      for (int mt = 0; mt < 4; mt++) \
        _Pragma("unroll") \
        for (int nt = 0; nt < 4; nt++) \
          acc[mt][nt] = __builtin_amdgcn_mfma_f32_16x16x32_bf16(af[mt], bfv[nt], acc[mt][nt], 0, 0, 0); \
    } \
    __syncthreads(); \
  }

// ---------------- Fused QKV projection GEMM ----------------
__global__ __launch_bounds__(256) void qkv_gemm(const u16* __restrict__ qa, const u16* __restrict__ ka,
                                                const u16* __restrict__ va,
                                                const u16* __restrict__ Wqb, const u16* __restrict__ Wkb,
                                                const u16* __restrict__ Wvb,
                                                const float* __restrict__ bqp, const float* __restrict__ bkp,
                                                const float* __restrict__ bvp, float qbscale,
                                                u16* __restrict__ qh, u16* __restrict__ kh,
                                                u16* __restrict__ vt) {
  constexpr int K = H_;
  __shared__ __align__(16) u16 SH[2][128*64];          // As / Bs, 16 KB each; SH[0] reused for V transpose
  u16* As = SH[0];
  u16* Bs = SH[1];
  const int tid = threadIdx.x;
  const int lane = tid & 63, wave = tid >> 6;
  const int lo = lane & 15, hi = lane >> 4;
  const int wr = wave >> 1, wc = wave & 1;
  const int wsel = blockIdx.y >> 3;
  const int m0 = blockIdx.x * 128, n0 = (blockIdx.y & 7) * 128;
  const u16* A  = wsel == 0 ? qa : wsel == 1 ? ka : va;
  const u16* Bm = wsel == 0 ? Wqb : wsel == 1 ? Wkb : Wvb;
  const float* bias = wsel == 0 ? bqp : wsel == 1 ? bkp : bvp;
  const float bscale = wsel == 0 ? qbscale : 1.0f;
  facc acc[4][4] = {};

  GEMM_KLOOP(A, Bm, As, Bs)

  if (wsel < 2) {
    u16* o = wsel == 0 ? qh : kh;
    #pragma unroll
    for (int nt = 0; nt < 4; nt++) {
      int n = n0 + wc*64 + nt*16 + lo;
      float bv = bias[n] * bscale;
      int hh = n >> 6, d = n & 63;
      #pragma unroll
      for (int mt = 0; mt < 4; mt++) {
        #pragma unroll
        for (int r = 0; r < 4; r++) {
          int m = m0 + wr*64 + mt*16 + hi*4 + r;
          int bb = m >> 11, s = m & (S_ - 1);
          o[(((size_t)bb*NH_ + hh)*S_ + s)*DK_ + d] = f2bf(acc[mt][nt][r] + bv);
        }
      }
    }
  } else {
    // V: tile -> LDS [64 d][128 s] (XOR-swizzled) -> coalesced d-major global writes.
    u16* scr = &SH[0][0];                     // 16 KB
    const int bb2 = m0 >> 11, s0r = m0 & (S_ - 1);
    #pragma unroll
    for (int p = 0; p < 2; p++) {            // head within n-range = wc
      __syncthreads();
      if (wc == p) {
        #pragma unroll
        for (int nt = 0; nt < 4; nt++) {
          int d = nt*16 + lo;
          float bv = bias[n0 + p*64 + d];
          #pragma unroll
          for (int mt = 0; mt < 4; mt++) {
            #pragma unroll
            for (int r = 0; r < 4; r++) {
              int s = wr*64 + mt*16 + hi*4 + r;
              *(u16*)((char*)scr + d*256 + ((s*2) ^ ((d & 7) << 4))) = f2bf(acc[mt][nt][r] + bv);
            }
          }
        }
      }
      __syncthreads();
      int hh = (n0 >> 6) + p;
      u16* vbase = vt + ((size_t)bb2*NH_ + hh) * DK_ * S_ + s0r;
      #pragma unroll
      for (int i = 0; i < 4; i++) {
        int idx = i*256 + tid;
        int d = idx >> 4, sc = idx & 15;
        bfrag v = *reinterpret_cast<const bfrag*>((char*)scr + d*256 + ((sc*16) ^ ((d & 7) << 4)));
        *reinterpret_cast<bfrag*>(vbase + (size_t)d*S_ + sc*8) = v;
      }
    }
  }
}

// ---------------- Output projection GEMM: out = xb @ Wo^T + bo (f32) ----------------
__global__ __launch_bounds__(256) void gemm_out(const u16* __restrict__ A, const u16* __restrict__ Bm,
                                                const float* __restrict__ bias, float* __restrict__ o) {
  constexpr int K = H_, N = H_;
  __shared__ __align__(16) u16 As[128*64];
  __shared__ __align__(16) u16 Bs[128*64];
  const int tid = threadIdx.x;
  const int lane = tid & 63, wave = tid >> 6;
  const int lo = lane & 15, hi = lane >> 4;
  const int wr = wave >> 1, wc = wave & 1;
  const int m0 = blockIdx.x * 128, n0 = blockIdx.y * 128;
  facc acc[4][4] = {};

  GEMM_KLOOP(A, Bm, As, Bs)

  #pragma unroll
  for (int nt = 0; nt < 4; nt++) {
    int n = n0 + wc*64 + nt*16 + lo;
    float bv = bias[n];
    #pragma unroll
    for (int mt = 0; mt < 4; mt++) {
      #pragma unroll
      for (int r = 0; r < 4; r++) {
        int m = m0 + wr*64 + mt*16 + hi*4 + r;
        o[(size_t)m*N + n] = acc[mt][nt][r] + bv;
      }
    }
  }
}

// ---------------- Flash attention v7c: fixed-M softmax, coalesced mask reads ----------------
__global__ __launch_bounds__(256, 4) void attn_kernel(const u16* __restrict__ Qh, const u16* __restrict__ Kh,
                                                      const u16* __restrict__ Vt, const uint32_t* __restrict__ mbytes,
                                                      u16* __restrict__ xout) {
  __shared__ __align__(16) u16 Ks[2][64*64];   // 8 KiB each, XOR-swizzled rows of 128 B
  __shared__ __align__(16) u16 Vs[2][64*64];
  const int tid = threadIdx.x;
  const int lane = tid & 63, wave = tid >> 6;
  const int l31 = lane & 31, hl = lane >> 5;
  const int gid = blockIdx.x;                  // XCD-bijective swizzle: 8 bh per XCD, qt inner
  const int bh = (gid & 7) * 8 + (gid >> 7);
  const int qt = (gid >> 3) & 15;
  const int b = bh >> 4, hd = bh & 15;
  const int q0 = qt * 128;
  const size_t bhS = (size_t)bh * S_;
  const int swz = (lane & 7) << 4;

  bfrag qf[4];
  {
    const u16* qrow = Qh + (bhS + q0 + wave*32 + l31) * DK_;
    #pragma unroll
    for (int t = 0; t < 4; t++) qf[t] = *reinterpret_cast<const bfrag*>(qrow + t*16 + hl*8);
  }
  // coalesced mask base: [qblk][c][wave][hl][l31][32B]; wave's chunk-read = contiguous 2 KB
  const int qblk = b*16 + qt;
  const char* mrowb = (const char*)mbytes + (size_t)qblk*262144 + wave*2048 + hl*1024 + l31*32;

  const int srow = wave*8 + (lane >> 3);
  const int scol = ((lane & 7) ^ (lane >> 3)) * 16;
  const char* ksrc = (const char*)(Kh + bhS * DK_) + (size_t)srow * 128 + scol;
  const char* vsrc = (const char*)(Vt + (size_t)bh * DK_ * S_) + (size_t)srow * (S_*2) + scol;

#define STAGE(buf, c) { \
    char* kl = (char*)Ks[buf] + wave*1024; \
    char* vl = (char*)Vs[buf] + wave*1024; \
    GLD16(ksrc + (size_t)(c)*8192,          kl); \
    GLD16(ksrc + (size_t)(c)*8192 + 4096,   kl + 4096); \
    GLD16(vsrc + (size_t)(c)*128,           vl); \
    GLD16(vsrc + (size_t)(c)*128 + 131072,  vl + 4096); \
  }

  float l_run = 0.f;                           // per-half-lane partial denominator
  f32x16 accO[2];
  #pragma unroll
  for (int e = 0; e < 16; e++) { accO[0][e] = 0.f; accO[1][e] = 0.f; }

  STAGE(0, 0);
  u32x4 mA_cur = *reinterpret_cast<const u32x4*>(mrowb);
  u32x4 mB_cur = *reinterpret_cast<const u32x4*>(mrowb + 16);
  __syncthreads();

  for (int c = 0; c < 32; c++) {
    const int cur = c & 1;
    if (c + 1 < 32) STAGE(cur ^ 1, c + 1);

    u32x4 mA = mA_cur, mB = mB_cur;
    if (c + 1 < 32) {
      const char* mn = mrowb + (size_t)(c + 1)*8192;
      mA_cur = *reinterpret_cast<const u32x4*>(mn);
      mB_cur = *reinterpret_cast<const u32x4*>(mn + 16);
    }

    // ---- C-init = -M - 1e36*maskbyte ----
    f32x16 s0, s1;
    #pragma unroll
    for (int r = 0; r < 16; r++) {
      float f0 = (float)((mA[r >> 2] >> ((r & 3) * 8)) & 0xffu);
      float f1 = (float)((mB[r >> 2] >> ((r & 3) * 8)) & 0xffu);
      s0[r] = __builtin_fmaf(f0, -1e36f, -8.0f);
      s1[r] = __builtin_fmaf(f1, -1e36f, -8.0f);
    }

    // ---- QK^T swapped ----
    const char* KsB = (const char*)Ks[cur];
    __builtin_amdgcn_s_setprio(1);
    #pragma unroll
    for (int t = 0; t < 4; t++) {
      bfrag k0 = *reinterpret_cast<const bfrag*>(KsB + l31*128        + ((t*32 + hl*16) ^ swz));
      bfrag k1 = *reinterpret_cast<const bfrag*>(KsB + (32 + l31)*128 + ((t*32 + hl*16) ^ swz));
      s0 = __builtin_amdgcn_mfma_f32_32x32x16_bf16(k0, qf[t], s0, 0, 0, 0);
      s1 = __builtin_amdgcn_mfma_f32_32x32x16_bf16(k1, qf[t], s1, 0, 0, 0);
    }
    __builtin_amdgcn_s_setprio(0);

    // ---- p = 2^s directly ----
    #pragma unroll
    for (int r = 0; r < 16; r++) {
      s0[r] = __builtin_amdgcn_exp2f(s0[r]);
      s1[r] = __builtin_amdgcn_exp2f(s1[r]);
    }
    float a8[8];
    #pragma unroll
    for (int r = 0; r < 8; r++) a8[r] = (s0[r] + s0[r+8]) + (s1[r] + s1[r+8]);
    l_run += ((a8[0] + a8[1]) + (a8[2] + a8[3])) + ((a8[4] + a8[5]) + (a8[6] + a8[7]));

    // ---- P -> PV A-frags in-register ----
    u32x4 pa[4];
    #pragma unroll
    for (int kt = 0; kt < 2; kt++) {
      uint32_t W[8];
      #pragma unroll
      for (int j = 0; j < 8; j++)
        W[j] = kt == 0 ? cvtpk_bf16(s0[2*j], s0[2*j+1]) : cvtpk_bf16(s1[2*j], s1[2*j+1]);
      u32x2 r02 = __builtin_amdgcn_permlane32_swap(W[0], W[2], false, false);
      u32x2 r13 = __builtin_amdgcn_permlane32_swap(W[1], W[3], false, false);
      u32x2 r46 = __builtin_amdgcn_permlane32_swap(W[4], W[6], false, false);
      u32x2 r57 = __builtin_amdgcn_permlane32_swap(W[5], W[7], false, false);
      pa[kt*2    ][0] = r02[0]; pa[kt*2    ][1] = r13[0]; pa[kt*2    ][2] = r02[1]; pa[kt*2    ][3] = r13[1];
      pa[kt*2 + 1][0] = r46[0]; pa[kt*2 + 1][1] = r57[0]; pa[kt*2 + 1][2] = r46[1]; pa[kt*2 + 1][3] = r57[1];
    }

    // ---- PV ----
    const char* VsB = (const char*)Vs[cur];
    __builtin_amdgcn_s_setprio(1);
    #pragma unroll
    for (int ks = 0; ks < 4; ks++) {
      bfrag pb = __builtin_bit_cast(bfrag, pa[ks]);
      bfrag v0 = *reinterpret_cast<const bfrag*>(VsB + l31*128        + ((ks*32 + hl*16) ^ swz));
      bfrag v1 = *reinterpret_cast<const bfrag*>(VsB + (32 + l31)*128 + ((ks*32 + hl*16) ^ swz));
      accO[0] = __builtin_amdgcn_mfma_f32_32x32x16_bf16(v0, pb, accO[0], 0, 0, 0);
      accO[1] = __builtin_amdgcn_mfma_f32_32x32x16_bf16(v1, pb, accO[1], 0, 0, 0);
    }
    __builtin_amdgcn_s_setprio(0);
    __syncthreads();
  }
#undef STAGE

  // ---- finalize ----
  float l_tot = l_run + __shfl_xor(l_run, 32);
  float linv = (l_tot > 0.f) ? (1.f / l_tot) : 0.f;
  u16* Xs = (u16*)Ks;
  {
    char* xb = (char*)Xs + (wave*32 + l31) * 128;
    #pragma unroll
    for (int dt = 0; dt < 2; dt++)
      #pragma unroll
      for (int j = 0; j < 8; j++) {
        uint32_t w = cvtpk_bf16(accO[dt][2*j] * linv, accO[dt][2*j+1] * linv);
        int d = dt*32 + ((2*j) & 3) + 8*((2*j) >> 2) + 4*hl;
        *reinterpret_cast<uint32_t*>(xb + ((d*2) ^ swz)) = w;
      }
  }
  __syncthreads();
  {
    int row = tid >> 1, d0 = (tid & 1) * 32;
    int rsw = (row & 7) << 4;
    u16* orow = xout + ((size_t)b * S_ + q0 + row) * H_ + hd * DK_ + d0;
    #pragma unroll
    for (int i = 0; i < 4; i++) {
      bfrag v = *reinterpret_cast<const bfrag*>((char*)Xs + row*128 + ((d0*2 + i*16) ^ rsw));
      *reinterpret_cast<bfrag*>((char*)orow + i*16) = v;
    }
  }
}

// ---------------- launch ----------------
extern "C" void kernel_launch(void* const* d_in, const int* in_sizes, int n_in,
                              void* d_out, int out_size, void* d_ws, size_t ws_size,
                              hipStream_t stream) {
  const float* query = (const float*)d_in[0];
  const float* key_  = (const float*)d_in[1];
  const float* value = (const float*)d_in[2];
  const int*   mask  = (const int*)d_in[3];
  const float* Wq = (const float*)d_in[4];
  const float* bq = (const float*)d_in[5];
  const float* Wk = (const float*)d_in[6];
  const float* bk = (const float*)d_in[7];
  const float* Wv = (const float*)d_in[8];
  const float* bv = (const float*)d_in[9];
  const float* Wo = (const float*)d_in[10];
  const float* bo = (const float*)d_in[11];
  float* out = (float*)d_out;

  char* ws = (char*)d_ws;
  const size_t MB = 1024 * 1024;
  u16* q_act = (u16*)(ws + 0*MB);
  u16* k_act = (u16*)(ws + 16*MB);
  u16* v_act = (u16*)(ws + 32*MB);
  u16* wq_b  = (u16*)(ws + 48*MB);
  u16* wk_b  = (u16*)(ws + 50*MB);
  u16* wv_b  = (u16*)(ws + 52*MB);
  u16* wo_b  = (u16*)(ws + 54*MB);
  u16* qh    = (u16*)(ws + 56*MB);
  u16* kh    = (u16*)(ws + 72*MB);
  u16* vt    = (u16*)(ws + 104*MB);
  u16* xb    = (u16*)(ws + 120*MB);
  uint32_t* mbytes = (uint32_t*)(ws + 136*MB);   // 16.8 MiB mask bytes (coalesced layout)

  const float QSCALE = 0.125f * 1.44269504088896f;   // 1/sqrt(DK) * log2(e), folded into Wq/bq

  prep_kernel<<<20480, 256, 0, stream>>>(query, key_, value, Wq, Wk, Wv, Wo, mask,
                                         q_act, k_act, v_act, wq_b, wk_b, wv_b, wo_b,
                                         mbytes, QSCALE);

  qkv_gemm<<<dim3(M_/128, 24), 256, 0, stream>>>(q_act, k_act, v_act, wq_b, wk_b, wv_b,
                                                 bq, bk, bv, QSCALE, qh, kh, vt);
  attn_kernel<<<1024, 256, 0, stream>>>(qh, kh, vt, mbytes, xb);
  gemm_out<<<dim3(M_/128, H_/128), 256, 0, stream>>>(xb, wo_b, bo, out);
}